// Round 11
// baseline (247.851 us; speedup 1.0000x reference)
//
#include <hip/hip_runtime.h>
#include <hip/hip_bf16.h>
#include <math.h>

#define BB 8
#define CC 256
#define NN 2048
static constexpr float BN_EPS = 1e-5f;

typedef _Float16 f16;
typedef f16 f16x4 __attribute__((ext_vector_type(4)));
typedef f16 f16x8 __attribute__((ext_vector_type(8)));
typedef float f32x4 __attribute__((ext_vector_type(4)));
typedef short s16x8 __attribute__((ext_vector_type(8)));     // 8 bf16 (MFMA operand)
typedef unsigned short u16x8 __attribute__((ext_vector_type(8)));  // 16B raw
typedef __hip_bfloat16 bf16;

#define APAD 40   // 16-bit-elem row stride (32 data + 8 pad) = 80B, 16B-aligned
#define XPAD 72   // 16-bit-elem row stride (64 data + 8 pad) = 144B, 16B-aligned

// ---------------------------------------------------------------------------
// Prep A: four C x C weight matrices -> hi/lo f16 planes (concatenated).
// ---------------------------------------------------------------------------
__global__ __launch_bounds__(256) void prep_w_kernel(
    const float* __restrict__ Wq, const float* __restrict__ Wk,
    const float* __restrict__ Wv, const float* __restrict__ Wt,
    f16* __restrict__ Whi, f16* __restrict__ Wlo)
{
    int idx = (blockIdx.x * 256 + threadIdx.x) * 8;   // over 4*C*C
    const float* s = (idx < 65536) ? Wq : (idx < 131072) ? Wk
                    : (idx < 196608) ? Wv : Wt;
    int off = idx & 65535;
    float4 a = *(const float4*)&s[off];
    float4 b = *(const float4*)&s[off + 4];
    float v[8] = {a.x, a.y, a.z, a.w, b.x, b.y, b.z, b.w};
    f16x8 h, l;
#pragma unroll
    for (int j = 0; j < 8; ++j) {
        f16 hh = (f16)v[j];
        f16 ll = (f16)(v[j] - (float)hh);
        h[j] = hh;
        l[j] = ll;
    }
    *(f16x8*)&Whi[idx] = h;
    *(f16x8*)&Wlo[idx] = l;
}

// ---------------------------------------------------------------------------
// Prep B: Xhi/Xlo[b][n][c] = split (f16) of x[b][c][n]  (LDS-tiled transpose)
// ---------------------------------------------------------------------------
__global__ __launch_bounds__(256) void prep_x_kernel(
    const float* __restrict__ x, f16* __restrict__ Xhi, f16* __restrict__ Xlo)
{
    const int b = blockIdx.z, c0 = blockIdx.y * 64, n0 = blockIdx.x * 64;
    const float* __restrict__ Xb = x + (size_t)b * CC * NN;
    f16* __restrict__ Oh = Xhi + (size_t)b * NN * CC;
    f16* __restrict__ Ol = Xlo + (size_t)b * NN * CC;
    __shared__ f16 Th[64][72];
    __shared__ f16 Tl[64][72];
    const int tid = threadIdx.x;
    const int r = tid >> 4, c4 = (tid & 15) * 4;
#pragma unroll
    for (int i = 0; i < 4; ++i) {
        int rr = r + i * 16;
        float4 v = *(const float4*)&Xb[(size_t)(c0 + rr) * NN + n0 + c4];
        float vv[4] = {v.x, v.y, v.z, v.w};
#pragma unroll
        for (int j = 0; j < 4; ++j) {
            f16 hh = (f16)vv[j];
            f16 ll = (f16)(vv[j] - (float)hh);
            Th[c4 + j][rr] = hh;
            Tl[c4 + j][rr] = ll;
        }
    }
    __syncthreads();
#pragma unroll
    for (int i = 0; i < 2; ++i) {
        int idx = tid + 256 * i;
        int n = idx >> 3, cg = (idx & 7) * 8;
        *(f16x8*)&Oh[(size_t)(n0 + n) * CC + c0 + cg] = *(f16x8*)&Th[n][cg];
        *(f16x8*)&Ol[(size_t)(n0 + n) * CC + c0 + cg] = *(f16x8*)&Tl[n][cg];
    }
}

// ---------------------------------------------------------------------------
// Kernel 1: projections via split-precision MFMA (hi*hi + hi*lo + lo*hi).
// which 0/1 -> Qhi/Khi f16 [b][n][c]; which 2 -> Vb16 bf16 [b][c][n] (+bv).
// ---------------------------------------------------------------------------
__global__ __launch_bounds__(256) void proj_mfma_kernel(
    const f16* __restrict__ Whi, const f16* __restrict__ Wlo,
    const f16* __restrict__ Xhi, const f16* __restrict__ Xlo,
    const float* __restrict__ bv,
    f16* __restrict__ Qhi, f16* __restrict__ Khi, bf16* __restrict__ Vb16)
{
    const int which = blockIdx.z >> 3;
    const int b     = blockIdx.z & 7;
    const f16* __restrict__ Wh = Whi + (size_t)which * CC * CC;
    const f16* __restrict__ Wl = Wlo + (size_t)which * CC * CC;
    const f16* __restrict__ Xh = Xhi + (size_t)b * NN * CC;
    const f16* __restrict__ Xl = Xlo + (size_t)b * NN * CC;

    const int m0 = blockIdx.y * 128;   // output channels
    const int n0 = blockIdx.x * 128;   // points

    __shared__ f16 Ah[128 * APAD];
    __shared__ f16 Al[128 * APAD];
    __shared__ f16 Bh[128 * APAD];
    __shared__ f16 Bl[128 * APAD];

    const int tid = threadIdx.x;
    const int wave = tid >> 6, lane = tid & 63;
    const int wr = (wave >> 1) * 64, wc = (wave & 1) * 64;
    const int lrow = lane & 15, lk = (lane >> 4) * 8;

    f32x4 acc[4][4] = {};

    for (int k0 = 0; k0 < CC; k0 += 32) {
#pragma unroll
        for (int i = 0; i < 2; ++i) {
            int idx = tid + 256 * i;
            int r = idx >> 2, ch = idx & 3;
            *(f16x8*)&Ah[r * APAD + ch * 8] =
                *(const f16x8*)&Wh[(size_t)(m0 + r) * CC + k0 + ch * 8];
            *(f16x8*)&Al[r * APAD + ch * 8] =
                *(const f16x8*)&Wl[(size_t)(m0 + r) * CC + k0 + ch * 8];
            *(f16x8*)&Bh[r * APAD + ch * 8] =
                *(const f16x8*)&Xh[(size_t)(n0 + r) * CC + k0 + ch * 8];
            *(f16x8*)&Bl[r * APAD + ch * 8] =
                *(const f16x8*)&Xl[(size_t)(n0 + r) * CC + k0 + ch * 8];
        }
        __syncthreads();
        f16x8 ah[4], al[4], bh[4], bl[4];
#pragma unroll
        for (int i = 0; i < 4; ++i) {
            ah[i] = *(const f16x8*)&Ah[(wr + i * 16 + lrow) * APAD + lk];
            al[i] = *(const f16x8*)&Al[(wr + i * 16 + lrow) * APAD + lk];
            bh[i] = *(const f16x8*)&Bh[(wc + i * 16 + lrow) * APAD + lk];
            bl[i] = *(const f16x8*)&Bl[(wc + i * 16 + lrow) * APAD + lk];
        }
#pragma unroll
        for (int i = 0; i < 4; ++i)
#pragma unroll
            for (int j = 0; j < 4; ++j) {
                acc[i][j] = __builtin_amdgcn_mfma_f32_16x16x32_f16(
                    ah[i], bh[j], acc[i][j], 0, 0, 0);
                acc[i][j] = __builtin_amdgcn_mfma_f32_16x16x32_f16(
                    ah[i], bl[j], acc[i][j], 0, 0, 0);
                acc[i][j] = __builtin_amdgcn_mfma_f32_16x16x32_f16(
                    al[i], bh[j], acc[i][j], 0, 0, 0);
            }
        __syncthreads();
    }

    if (which < 2) {
        f16* __restrict__ Oh = ((which == 0) ? Qhi : Khi) + (size_t)b * NN * CC;
#pragma unroll
        for (int i = 0; i < 4; ++i) {
            int cb = m0 + wr + i * 16 + (lane >> 4) * 4;
#pragma unroll
            for (int j = 0; j < 4; ++j) {
                int n = n0 + wc + j * 16 + lrow;
                f16x4 hv;
#pragma unroll
                for (int q = 0; q < 4; ++q) hv[q] = (f16)acc[i][j][q];
                *(f16x4*)&Oh[(size_t)n * CC + cb] = hv;
            }
        }
    } else {
        bf16* __restrict__ Vb = Vb16 + (size_t)b * CC * NN;
#pragma unroll
        for (int i = 0; i < 4; ++i) {
            int cb = m0 + wr + i * 16 + (lane >> 4) * 4;
#pragma unroll
            for (int q = 0; q < 4; ++q) {
                float bvv = bv[cb + q];
#pragma unroll
                for (int j = 0; j < 4; ++j) {
                    int n = n0 + wc + j * 16 + lrow;
                    Vb[(size_t)(cb + q) * NN + n] = __float2bfloat16(acc[i][j][q] + bvv);
                }
            }
        }
    }
}

// ---------------------------------------------------------------------------
// Kernel 2: energy = Qhi . Khi^T -> fp32 logits (LDS-staged hi-only).
// ---------------------------------------------------------------------------
__global__ __launch_bounds__(256) void energy_mfma_kernel(
    const f16* __restrict__ Qhi, const f16* __restrict__ Khi,
    float* __restrict__ ATT)
{
    const int b = blockIdx.z;
    const int n0 = blockIdx.y * 128;
    const int m0 = blockIdx.x * 128;
    const f16* __restrict__ Qh = Qhi + (size_t)b * NN * CC;
    const f16* __restrict__ Kh = Khi + (size_t)b * NN * CC;
    float* __restrict__ Eb = ATT + (size_t)b * NN * NN;

    __shared__ f16 Ah[128 * APAD];
    __shared__ f16 Bh[128 * APAD];

    const int tid = threadIdx.x;
    const int wave = tid >> 6, lane = tid & 63;
    const int wr = (wave >> 1) * 64, wc = (wave & 1) * 64;
    const int lrow = lane & 15, lk = (lane >> 4) * 8;

    f32x4 acc[4][4] = {};

    for (int k0 = 0; k0 < CC; k0 += 32) {
#pragma unroll
        for (int i = 0; i < 2; ++i) {
            int idx = tid + 256 * i;
            int r = idx >> 2, ch = idx & 3;
            *(f16x8*)&Ah[r * APAD + ch * 8] =
                *(const f16x8*)&Qh[(size_t)(n0 + r) * CC + k0 + ch * 8];
            *(f16x8*)&Bh[r * APAD + ch * 8] =
                *(const f16x8*)&Kh[(size_t)(m0 + r) * CC + k0 + ch * 8];
        }
        __syncthreads();
        f16x8 af[4], bf[4];
#pragma unroll
        for (int i = 0; i < 4; ++i) {
            af[i] = *(const f16x8*)&Ah[(wr + i * 16 + lrow) * APAD + lk];
            bf[i] = *(const f16x8*)&Bh[(wc + i * 16 + lrow) * APAD + lk];
        }
#pragma unroll
        for (int i = 0; i < 4; ++i)
#pragma unroll
            for (int j = 0; j < 4; ++j)
                acc[i][j] = __builtin_amdgcn_mfma_f32_16x16x32_f16(
                    af[i], bf[j], acc[i][j], 0, 0, 0);
        __syncthreads();
    }

#pragma unroll
    for (int i = 0; i < 4; ++i)
#pragma unroll
        for (int q = 0; q < 4; ++q) {
            int row = n0 + wr + i * 16 + (lane >> 4) * 4 + q;
#pragma unroll
            for (int j = 0; j < 4; ++j) {
                int col = m0 + wc + j * 16 + lrow;
                Eb[(size_t)row * NN + col] = acc[i][j][q];
            }
        }
}

// ---------------------------------------------------------------------------
// Kernel 3: row softmax; fp32 logits in, normalized bf16 out IN PLACE
// (packed at the row start; bf16 row stride = 2*NN).
// ---------------------------------------------------------------------------
__global__ __launch_bounds__(256) void softmax_kernel(float* __restrict__ ATT)
{
    const size_t row = blockIdx.x;
    float* __restrict__ R = ATT + row * NN;
    const int tid = threadIdx.x;
    const int wave = tid >> 6, lane = tid & 63;

    float e[8];
#pragma unroll
    for (int j = 0; j < 8; ++j) e[j] = R[tid + 256 * j];

    float mx = e[0];
#pragma unroll
    for (int j = 1; j < 8; ++j) mx = fmaxf(mx, e[j]);
#pragma unroll
    for (int s = 1; s < 64; s <<= 1) mx = fmaxf(mx, __shfl_xor(mx, s));

    __shared__ float redm[4];
    if (lane == 0) redm[wave] = mx;
    __syncthreads();
    mx = fmaxf(fmaxf(redm[0], redm[1]), fmaxf(redm[2], redm[3]));

    float s = 0.f;
#pragma unroll
    for (int j = 0; j < 8; ++j) { e[j] = __expf(e[j] - mx); s += e[j]; }
#pragma unroll
    for (int t = 1; t < 64; t <<= 1) s += __shfl_xor(s, t);

    __shared__ float reds[4];
    if (lane == 0) reds[wave] = s;
    __syncthreads();
    s = reds[0] + reds[1] + reds[2] + reds[3];

    const float inv = 1.f / s;
    bf16* __restrict__ R16 = (bf16*)R;
#pragma unroll
    for (int j = 0; j < 8; ++j)
        R16[tid + 256 * j] = __float2bfloat16(e[j] * inv);
}

// ---------------------------------------------------------------------------
// Kernel 4: fused column-sum + transpose (XOR-swizzled LDS tile).
// Logical T[row][col] stored at column-granule (col>>3)^((row>>3)&7) —
// breaks the 16-way bank conflict of the scatter while keeping 16B-aligned
// vector reads on both consumers.
// ---------------------------------------------------------------------------
__global__ __launch_bounds__(256) void colsum_tr_kernel(
    float* __restrict__ ATT, float* __restrict__ colsum)
{
    const int b = blockIdx.z;
    const int n0 = blockIdx.x * 64;
    const int m0 = blockIdx.y * 64;
    bf16* __restrict__ A16 = (bf16*)(ATT + (size_t)b * NN * NN);

    __shared__ bf16 T[64][72];
    const int tid = threadIdx.x;

#pragma unroll
    for (int i = 0; i < 2; ++i) {
        int idx = tid + 256 * i;
        int r = idx >> 3, ch = idx & 7;    // attn row n0+r, m-chunk ch*8
        u16x8 v = *(const u16x8*)&A16[(size_t)(n0 + r) * (2 * NN) + m0 + ch * 8];
        int pc = (((r >> 3) ^ ch) << 3) + (r & 7);   // swizzled column for col=r
#pragma unroll
        for (int j = 0; j < 8; ++j) T[ch * 8 + j][pc] = ((bf16*)&v)[j];
    }
    __syncthreads();

    // column-sum partials: 4 threads per m-row, each sums 16 n's
    {
        int m = tid >> 2, q = tid & 3;
        int mh = (m >> 3) & 7;
        float s = 0.f;
#pragma unroll
        for (int j = 0; j < 16; ++j) {
            int col = q * 16 + j;
            s += __bfloat162float(T[m][(((col >> 3) ^ mh) << 3) + (col & 7)]);
        }
        s += __shfl_xor(s, 1);
        s += __shfl_xor(s, 2);
        if (q == 0) atomicAdd(&colsum[b * NN + m0 + m], s);
    }

    // transposed write: row m at bf16 offset m*2NN + NN (+ n)
#pragma unroll
    for (int i = 0; i < 2; ++i) {
        int idx = tid + 256 * i;
        int mr = idx >> 3, ch = idx & 7;
        int pg = (ch ^ ((mr >> 3) & 7)) << 3;
        u16x8 w = *(const u16x8*)&T[mr][pg];
        *(u16x8*)&A16[(size_t)(m0 + mr) * (2 * NN) + NN + n0 + ch * 8] = w;
    }
}

// ---------------------------------------------------------------------------
// Kernel 5: x_r_raw = V . A^T (bf16 MFMA). 64x64 tile, BK=64, grid 1024
// blocks (4/CU, 16 waves/CU) — occupancy-driven latency hiding.
// Epilogue applies rcv[n] and writes Dt16[n][c] = (f16)(x - x_r_raw*rcv).
// ---------------------------------------------------------------------------
__global__ __launch_bounds__(256) void xr_mfma_kernel(
    const bf16* __restrict__ Vb16, const float* __restrict__ ATT,
    const float* __restrict__ colsum, const float* __restrict__ x,
    f16* __restrict__ Dt16)
{
    const int b  = blockIdx.z;
    const int c0 = blockIdx.y * 64;
    const int n0 = blockIdx.x * 64;
    const bf16* __restrict__ Vb = Vb16 + (size_t)b * CC * NN;
    const bf16* __restrict__ A16 = (const bf16*)(ATT + (size_t)b * NN * NN);
    const float* __restrict__ Xb = x + (size_t)b * CC * NN;
    f16* __restrict__ Db = Dt16 + (size_t)b * NN * CC;

    __shared__ bf16 Asl[64 * XPAD];
    __shared__ bf16 Bsl[64 * XPAD];
    __shared__ float rcvL[64];

    const int tid = threadIdx.x;
    if (tid < 64) rcvL[tid] = 1.f / (1e-9f + colsum[b * NN + n0 + tid]);

    const int wave = tid >> 6, lane = tid & 63;
    const int wr = (wave >> 1) * 32, wc = (wave & 1) * 32;
    const int lrow = lane & 15, lk = (lane >> 4) * 8;

    f32x4 acc[2][2] = {};

    for (int k0 = 0; k0 < NN; k0 += 64) {
#pragma unroll
        for (int i = 0; i < 2; ++i) {
            int idx = tid + 256 * i;
            int r = idx >> 3, ch = idx & 7;
            *(u16x8*)&Asl[r * XPAD + ch * 8] =
                *(const u16x8*)&Vb[(size_t)(c0 + r) * NN + k0 + ch * 8];
            // A^T row n at bf16 offset n*2NN + NN
            *(u16x8*)&Bsl[r * XPAD + ch * 8] =
                *(const u16x8*)&A16[(size_t)(n0 + r) * (2 * NN) + NN + k0 + ch * 8];
        }
        __syncthreads();
#pragma unroll
        for (int ks = 0; ks < 2; ++ks) {
            s16x8 af[2], bf[2];
#pragma unroll
            for (int i = 0; i < 2; ++i) {
                af[i] = *(const s16x8*)&Asl[(wr + i * 16 + lrow) * XPAD + ks * 32 + lk];
                bf[i] = *(const s16x8*)&Bsl[(wc + i * 16 + lrow) * XPAD + ks * 32 + lk];
            }
#pragma unroll
            for (int i = 0; i < 2; ++i)
#pragma unroll
                for (int j = 0; j < 2; ++j)
                    acc[i][j] = __builtin_amdgcn_mfma_f32_16x16x32_bf16(
                        af[i], bf[j], acc[i][j], 0, 0, 0);
        }
        __syncthreads();
    }

#pragma unroll
    for (int i = 0; i < 2; ++i) {
        int cb = c0 + wr + i * 16 + (lane >> 4) * 4;
#pragma unroll
        for (int j = 0; j < 2; ++j) {
            int ln = wc + j * 16 + lrow;
            int n = n0 + ln;
            float rc = rcvL[ln];
            f16x4 dv;
#pragma unroll
            for (int q = 0; q < 4; ++q)
                dv[q] = (f16)(Xb[(size_t)(cb + q) * NN + n] - acc[i][j][q] * rc);
            *(f16x4*)&Db[(size_t)n * CC + cb] = dv;
        }
    }
}

// ---------------------------------------------------------------------------
// Kernel 6: XZ(bf16) = alpha*(Wt*Dt16 + bt) + beta; BN sums from fp32 values.
// ---------------------------------------------------------------------------
__global__ __launch_bounds__(256) void xz_mfma_kernel(
    const f16* __restrict__ Whi, const f16* __restrict__ Dt16,
    const float* __restrict__ bt, const float* __restrict__ alpha,
    const float* __restrict__ beta, bf16* __restrict__ XZ,
    float* __restrict__ bnsum, float* __restrict__ bnsumsq)
{
    const int b = blockIdx.z;
    const int m0 = blockIdx.y * 128;
    const int n0 = blockIdx.x * 128;
    const f16* __restrict__ Wb = Whi + (size_t)3 * CC * CC;   // Wt (hi)
    const f16* __restrict__ Db = Dt16 + (size_t)b * NN * CC;
    bf16* __restrict__ Zb = XZ + (size_t)b * CC * NN;

    __shared__ f16 Asl[128 * APAD];
    __shared__ f16 Bsl[128 * APAD];

    const int tid = threadIdx.x;
    const int wave = tid >> 6, lane = tid & 63;
    const int wr = (wave >> 1) * 64, wc = (wave & 1) * 64;
    const int lrow = lane & 15, lk = (lane >> 4) * 8;

    f32x4 acc[4][4] = {};

    for (int k0 = 0; k0 < CC; k0 += 32) {
#pragma unroll
        for (int i = 0; i < 2; ++i) {
            int idx = tid + 256 * i;
            int r = idx >> 2, ch = idx & 3;
            *(f16x8*)&Asl[r * APAD + ch * 8] =
                *(const f16x8*)&Wb[(size_t)(m0 + r) * CC + k0 + ch * 8];
            *(f16x8*)&Bsl[r * APAD + ch * 8] =
                *(const f16x8*)&Db[(size_t)(n0 + r) * CC + k0 + ch * 8];
        }
        __syncthreads();
        f16x8 af[4], bf[4];
#pragma unroll
        for (int i = 0; i < 4; ++i) {
            af[i] = *(const f16x8*)&Asl[(wr + i * 16 + lrow) * APAD + lk];
            bf[i] = *(const f16x8*)&Bsl[(wc + i * 16 + lrow) * APAD + lk];
        }
#pragma unroll
        for (int i = 0; i < 4; ++i)
#pragma unroll
            for (int j = 0; j < 4; ++j)
                acc[i][j] = __builtin_amdgcn_mfma_f32_16x16x32_f16(
                    af[i], bf[j], acc[i][j], 0, 0, 0);
        __syncthreads();
    }

#pragma unroll
    for (int i = 0; i < 4; ++i) {
#pragma unroll
        for (int q = 0; q < 4; ++q) {
            int o = m0 + wr + i * 16 + (lane >> 4) * 4 + q;
            float al = alpha[o], be = beta[o], bb = bt[o];
            float s1 = 0.f, s2 = 0.f;
#pragma unroll
            for (int j = 0; j < 4; ++j) {
                int n = n0 + wc + j * 16 + lrow;
                float z = al * (acc[i][j][q] + bb) + be;
                Zb[(size_t)o * NN + n] = __float2bfloat16(z);
                s1 += z; s2 += z * z;
            }
#pragma unroll
            for (int d = 1; d < 16; d <<= 1) {
                s1 += __shfl_xor(s1, d);
                s2 += __shfl_xor(s2, d);
            }
            if (lrow == 0) {
                atomicAdd(&bnsum[o], s1);
                atomicAdd(&bnsumsq[o], s2);
            }
        }
    }
}

// ---------------------------------------------------------------------------
// Kernel 7: out = x + relu(gamma*(XZ-mean)*rsqrt(var+eps)+beta)
// ---------------------------------------------------------------------------
__global__ __launch_bounds__(256) void final_kernel(
    const float* __restrict__ x, const bf16* __restrict__ XZ,
    const float* __restrict__ bnsum, const float* __restrict__ bnsumsq,
    const float* __restrict__ gamma, const float* __restrict__ bbeta,
    float* __restrict__ out)
{
    const int i4 = blockIdx.x * 256 + threadIdx.x;
    const int elem = i4 * 4;
    const int c = (elem / NN) % CC;
    const float inv_cnt = 1.f / (float)(BB * NN);
    const float mean = bnsum[c] * inv_cnt;
    const float var  = bnsumsq[c] * inv_cnt - mean * mean;
    const float rs = rsqrtf(var + BN_EPS);
    const float g = gamma[c], bb = bbeta[c];

    ushort4 zu = *(const ushort4*)&XZ[elem];
    float4 xv = *(const float4*)&x[elem];
    float z0 = __uint_as_float((unsigned)zu.x << 16);
    float z1 = __uint_as_float((unsigned)zu.y << 16);
    float z2 = __uint_as_float((unsigned)zu.z << 16);
    float z3 = __uint_as_float((unsigned)zu.w << 16);
    float4 o;
    o.x = xv.x + fmaxf(g * (z0 - mean) * rs + bb, 0.f);
    o.y = xv.y + fmaxf(g * (z1 - mean) * rs + bb, 0.f);
    o.z = xv.z + fmaxf(g * (z2 - mean) * rs + bb, 0.f);
    o.w = xv.w + fmaxf(g * (z3 - mean) * rs + bb, 0.f);
    *(float4*)&out[elem] = o;
}

// ---------------------------------------------------------------------------

extern "C" void kernel_launch(void* const* d_in, const int* in_sizes, int n_in,
                              void* d_out, int out_size, void* d_ws, size_t ws_size,
                              hipStream_t stream) {
    const float* x     = (const float*)d_in[0];
    const float* Wq    = (const float*)d_in[1];
    const float* Wk    = (const float*)d_in[2];
    const float* Wv    = (const float*)d_in[3];
    const float* bv    = (const float*)d_in[4];
    const float* Wt    = (const float*)d_in[5];
    const float* bt    = (const float*)d_in[6];
    const float* gamma = (const float*)d_in[7];
    const float* bbeta = (const float*)d_in[8];
    const float* alpha = (const float*)d_in[9];
    const float* beta  = (const float*)d_in[10];
    float* out = (float*)d_out;

    const size_t BCN = (size_t)BB * CC * NN;   // 4,194,304 elements
    const size_t WSZ = (size_t)4 * CC * CC;    // 262,144

    f16* Whi = (f16*)d_ws;                     // 4 x [C][C] hi
    f16* Wlo = Whi + WSZ;                      // 4 x [C][C] lo
    bf16* Vb16 = (bf16*)(Wlo + WSZ);           // [B][C][N] bf16
    f16* Qhi = (f16*)(Vb16 + BCN);             // [B][N][C]
    f16* Khi = Qhi + BCN;                      // [B][N][C]
    float* ATT = (float*)(Khi + BCN);          // [B][N][N]: bf16 attn rows (1st half) + bf16 attn^T rows (2nd half)
    bf16* XZ = (bf16*)(ATT + (size_t)BB * NN * NN);  // [B][C][N] bf16
    float* colsum  = (float*)(XZ + BCN);       // [B][N]
    float* bnsum   = colsum + (size_t)BB * NN; // [C]
    float* bnsumsq = bnsum + CC;               // [C]

    // Xhi/Xlo overlay batch-0's ATT slab (dead by the time energy writes it).
    f16* Xhi = (f16*)ATT;                      // [B][N][C]
    f16* Xlo = Xhi + BCN;                      // [B][N][C]
    f16* Dt16 = Qhi;                           // reuse Qhi after energy

    hipMemsetAsync(colsum, 0, (size_t)(BB * NN + 2 * CC) * sizeof(float), stream);

    prep_w_kernel<<<dim3(4 * CC * CC / 2048), 256, 0, stream>>>(
        Wq, Wk, Wv, Wt, Whi, Wlo);
    prep_x_kernel<<<dim3(NN / 64, CC / 64, BB), 256, 0, stream>>>(x, Xhi, Xlo);
    proj_mfma_kernel<<<dim3(NN / 128, CC / 128, 3 * BB), 256, 0, stream>>>(
        Whi, Wlo, Xhi, Xlo, bv, Qhi, Khi, Vb16);
    energy_mfma_kernel<<<dim3(NN / 128, NN / 128, BB), 256, 0, stream>>>(
        Qhi, Khi, ATT);
    softmax_kernel<<<dim3(BB * NN), 256, 0, stream>>>(ATT);
    colsum_tr_kernel<<<dim3(NN / 64, NN / 64, BB), 256, 0, stream>>>(ATT, colsum);
    xr_mfma_kernel<<<dim3(NN / 64, CC / 64, BB), 256, 0, stream>>>(
        Vb16, ATT, colsum, x, Dt16);
    xz_mfma_kernel<<<dim3(NN / 128, CC / 128, BB), 256, 0, stream>>>(
        Whi, Dt16, bt, alpha, beta, XZ, bnsum, bnsumsq);
    final_kernel<<<dim3((int)(BCN / 4 / 256)), 256, 0, stream>>>(
        x, XZ, bnsum, bnsumsq, gamma, bbeta, out);
}